// Round 2
// baseline (3313.823 us; speedup 1.0000x reference)
//
#include <hip/hip_runtime.h>
#include <math.h>

#define S_DIM 2048
#define H_DIM 2048
#define NH 16
#define HD 128

// ---------------- GEMM: C = A @ B + bias (all fp32, row-major) ----------------
#define BM 128
#define BN 128
#define BK 16

__global__ __launch_bounds__(256) void gemm_f32(
    const float* __restrict__ A, const float* __restrict__ B,
    const float* __restrict__ bias, float* __restrict__ C,
    int M, int N, int K)
{
  __shared__ float As[BK][BM + 4];   // staged transposed: As[k][m]
  __shared__ float Bs[BK][BN + 4];   // Bs[k][n]
  const int tid = threadIdx.x;
  const int bm = blockIdx.y * BM;
  const int bn = blockIdx.x * BN;
  const int ty = tid >> 4;   // 0..15
  const int tx = tid & 15;   // 0..15

  float acc[8][8];
  #pragma unroll
  for (int i = 0; i < 8; ++i)
    #pragma unroll
    for (int j = 0; j < 8; ++j) acc[i][j] = 0.f;

  for (int k0 = 0; k0 < K; k0 += BK) {
    #pragma unroll
    for (int l = 0; l < 2; ++l) {
      int idx = tid + l * 256;                 // 0..511
      int ar = idx >> 2, ac = (idx & 3) << 2;  // A tile: 128 rows x 16 cols
      float4 av = *(const float4*)(A + (size_t)(bm + ar) * K + k0 + ac);
      As[ac + 0][ar] = av.x;
      As[ac + 1][ar] = av.y;
      As[ac + 2][ar] = av.z;
      As[ac + 3][ar] = av.w;
      int br = idx >> 5, bc = (idx & 31) << 2; // B tile: 16 rows x 128 cols
      *(float4*)&Bs[br][bc] = *(const float4*)(B + (size_t)(k0 + br) * N + bn + bc);
    }
    __syncthreads();
    #pragma unroll
    for (int kk = 0; kk < BK; ++kk) {
      float a[8], b[8];
      *(float4*)&a[0] = *(const float4*)&As[kk][ty * 8];
      *(float4*)&a[4] = *(const float4*)&As[kk][ty * 8 + 4];
      *(float4*)&b[0] = *(const float4*)&Bs[kk][tx * 8];
      *(float4*)&b[4] = *(const float4*)&Bs[kk][tx * 8 + 4];
      #pragma unroll
      for (int i = 0; i < 8; ++i)
        #pragma unroll
        for (int j = 0; j < 8; ++j)
          acc[i][j] = fmaf(a[i], b[j], acc[i][j]);
    }
    __syncthreads();
  }

  const float* bp = bias + bn + tx * 8;
  float bv[8];
  #pragma unroll
  for (int j = 0; j < 8; ++j) bv[j] = bp[j];
  #pragma unroll
  for (int i = 0; i < 8; ++i) {
    int row = bm + ty * 8 + i;
    float* cp = C + (size_t)row * N + bn + tx * 8;
    float4 c0 = { acc[i][0] + bv[0], acc[i][1] + bv[1], acc[i][2] + bv[2], acc[i][3] + bv[3] };
    float4 c1 = { acc[i][4] + bv[4], acc[i][5] + bv[5], acc[i][6] + bv[6], acc[i][7] + bv[7] };
    *(float4*)cp = c0;
    *(float4*)(cp + 4) = c1;
  }
}

// ---------------- RoPE (in-place on Q and K) ----------------
// Element (s, h, i), i in [0,64): pair (i, i+64) of each 128-dim head.
__global__ __launch_bounds__(256) void rope_kernel(float* __restrict__ Q, float* __restrict__ K)
{
  int t = blockIdx.x * blockDim.x + threadIdx.x;   // S*NH*64 threads
  int i = t & 63;
  int h = (t >> 6) & (NH - 1);
  int s = t >> 10;
  // inv_freq computed in double to avoid fp32-pow mismatch vs reference
  float invf = (float)pow(10000.0, -(double)i * (1.0 / 64.0));
  float ang = (float)s * invf;
  float sv, cv;
  sincosf(ang, &sv, &cv);
  size_t base = (size_t)s * H_DIM + h * HD + i;
  float q1 = Q[base], q2 = Q[base + 64];
  Q[base]      = q1 * cv - q2 * sv;
  Q[base + 64] = q2 * cv + q1 * sv;
  float k1 = K[base], k2 = K[base + 64];
  K[base]      = k1 * cv - k2 * sv;
  K[base + 64] = k2 * cv + k1 * sv;
}

// ---------------- Flash attention (fp32, online softmax) ----------------
// 16 lanes per query (lane owns 8 of 128 dims), 4 queries per wave, 4 waves/block.
// O may alias Q: each group reads only its own Q row (at start) and writes only
// that row (at end); no cross-thread access to the slice.
__global__ __launch_bounds__(256) void attn_flash(
    const float* __restrict__ Q, const float* __restrict__ K,
    const float* __restrict__ V, float* __restrict__ O)
{
  const int lane = threadIdx.x & 63;
  const int wave = threadIdx.x >> 6;
  const int grp  = lane >> 4;     // 4 query-groups per wave
  const int gl   = lane & 15;     // lane-in-group: owns dims gl*8 .. gl*8+7
  const int h    = blockIdx.y;
  const int q_idx = blockIdx.x * 16 + wave * 4 + grp;
  const float scale = 0.08838834764831845f;  // 1/sqrt(128)

  const float* qp = Q + (size_t)q_idx * H_DIM + h * HD + gl * 8;
  float4 q0 = *(const float4*)qp;
  float4 q1 = *(const float4*)(qp + 4);

  const float* kr = K + h * HD + gl * 8;
  const float* vr = V + h * HD + gl * 8;

  float m = -3.402823466e+38f;  // -FLT_MAX
  float l = 0.f;
  float4 o0 = {0.f, 0.f, 0.f, 0.f};
  float4 o1 = {0.f, 0.f, 0.f, 0.f};

  #pragma unroll 4
  for (int j = 0; j < S_DIM; ++j) {
    float4 k0 = *(const float4*)kr;
    float4 k1 = *(const float4*)(kr + 4);
    float4 v0 = *(const float4*)vr;
    float4 v1 = *(const float4*)(vr + 4);
    kr += H_DIM; vr += H_DIM;

    float p = q0.x * k0.x + q0.y * k0.y + q0.z * k0.z + q0.w * k0.w
            + q1.x * k1.x + q1.y * k1.y + q1.z * k1.z + q1.w * k1.w;
    p += __shfl_xor(p, 1);
    p += __shfl_xor(p, 2);
    p += __shfl_xor(p, 4);
    p += __shfl_xor(p, 8);
    float s = p * scale;

    if (s > m) {             // uniform within the 16-lane group
      float corr = __expf(m - s);   // first iter: exp(-inf) = 0
      l *= corr;
      o0.x *= corr; o0.y *= corr; o0.z *= corr; o0.w *= corr;
      o1.x *= corr; o1.y *= corr; o1.z *= corr; o1.w *= corr;
      m = s;
    }
    float pe = __expf(s - m);
    l += pe;
    o0.x = fmaf(pe, v0.x, o0.x);
    o0.y = fmaf(pe, v0.y, o0.y);
    o0.z = fmaf(pe, v0.z, o0.z);
    o0.w = fmaf(pe, v0.w, o0.w);
    o1.x = fmaf(pe, v1.x, o1.x);
    o1.y = fmaf(pe, v1.y, o1.y);
    o1.z = fmaf(pe, v1.z, o1.z);
    o1.w = fmaf(pe, v1.w, o1.w);
  }

  float inv = 1.f / l;
  float* op = O + (size_t)q_idx * H_DIM + h * HD + gl * 8;
  float4 r0 = { o0.x * inv, o0.y * inv, o0.z * inv, o0.w * inv };
  float4 r1 = { o1.x * inv, o1.y * inv, o1.z * inv, o1.w * inv };
  *(float4*)op = r0;
  *(float4*)(op + 4) = r1;
}

// ---------------- launch ----------------
extern "C" void kernel_launch(void* const* d_in, const int* in_sizes, int n_in,
                              void* d_out, int out_size, void* d_ws, size_t ws_size,
                              hipStream_t stream)
{
  const float* X  = (const float*)d_in[0];
  const float* wq = (const float*)d_in[1];
  const float* bq = (const float*)d_in[2];
  const float* wk = (const float*)d_in[3];
  const float* bk = (const float*)d_in[4];
  const float* wv = (const float*)d_in[5];
  const float* bv = (const float*)d_in[6];
  const float* wo = (const float*)d_in[7];
  const float* bo = (const float*)d_in[8];
  float* out = (float*)d_out;

  const size_t slab = (size_t)S_DIM * H_DIM;  // elements
  float* Qb = (float*)d_ws;
  float* Kb = Qb + slab;
  float* Vb = Kb + slab;

  dim3 gGemm(H_DIM / BN, S_DIM / BM);  // (16,16)

  gemm_f32<<<gGemm, 256, 0, stream>>>(X, wq, bq, Qb, S_DIM, H_DIM, H_DIM);
  gemm_f32<<<gGemm, 256, 0, stream>>>(X, wk, bk, Kb, S_DIM, H_DIM, H_DIM);
  gemm_f32<<<gGemm, 256, 0, stream>>>(X, wv, bv, Vb, S_DIM, H_DIM, H_DIM);

  rope_kernel<<<(S_DIM * NH * 64) / 256, 256, 0, stream>>>(Qb, Kb);

  dim3 gAttn(S_DIM / 16, NH);
  attn_flash<<<gAttn, 256, 0, stream>>>(Qb, Kb, Vb, Qb /* O overwrites Q slab */);

  gemm_f32<<<gGemm, 256, 0, stream>>>(Qb, wo, bo, out, S_DIM, H_DIM, H_DIM);
}

// Round 10
// 1250.375 us; speedup vs baseline: 2.6503x; 2.6503x over previous
//
#include <hip/hip_runtime.h>
#include <math.h>

#define S_DIM 2048
#define H_DIM 2048
#define NH 16
#define HD 128
#define QSCALE 0.08838834764831845f

typedef __attribute__((ext_vector_type(8))) short short8;
typedef __attribute__((ext_vector_type(4))) float f32x4;
typedef unsigned short ushort_t;

static __device__ __forceinline__ unsigned short f2bf(float x) {
  union { float f; unsigned u; } v; v.f = x;
  unsigned r = v.u + 0x7fffu + ((v.u >> 16) & 1u);
  return (unsigned short)(r >> 16);
}
static __device__ __forceinline__ float bf2f(unsigned short h) {
  union { float f; unsigned u; } v; v.u = ((unsigned)h) << 16;
  return v.f;
}

// ---------- transpose+split: W[k][n] fp32 -> Wt[n][k] split bf16 (hi/lo) ----------
__global__ __launch_bounds__(256) void transpose_split(
    const float* __restrict__ W, ushort_t* __restrict__ Th, ushort_t* __restrict__ Tl)
{
  __shared__ float T[64][65];
  const int tid = threadIdx.x;
  const int k0 = blockIdx.y * 64, n0 = blockIdx.x * 64;
  #pragma unroll
  for (int it = 0; it < 4; ++it) {
    int r = (tid >> 4) + it * 16;
    int c = (tid & 15) * 4;
    float4 v = *(const float4*)(W + (size_t)(k0 + r) * H_DIM + n0 + c);
    T[r][c] = v.x; T[r][c + 1] = v.y; T[r][c + 2] = v.z; T[r][c + 3] = v.w;
  }
  __syncthreads();
  const int nl = tid & 63;
  #pragma unroll
  for (int p = 0; p < 4; ++p) {
    int kl = (tid >> 6) * 4 + p * 16;
    ushort_t h4[4], l4[4];
    #pragma unroll
    for (int i = 0; i < 4; ++i) {
      float x = T[kl + i][nl];
      h4[i] = f2bf(x);
      l4[i] = f2bf(x - bf2f(h4[i]));
    }
    size_t o = (size_t)(n0 + nl) * H_DIM + k0 + kl;
    *(uint2*)(Th + o) = *(const uint2*)h4;
    *(uint2*)(Tl + o) = *(const uint2*)l4;
  }
}

// ---------- GEMM: C = A(fp32) @ Wt^T + bias via split-bf16 3-term MFMA ----------
// A row-major [M][K] fp32; B given TRANSPOSED split bf16 Bt[n][k] (hi/lo).
// 4 waves, wave w owns rows [bm+w*32, +32) x all 128 cols. No LDS, no barriers.
// MODE 0: Cf fp32 (+bias).    MODE 1: rope(bias-added)*scale -> split Chi/Clo.
// MODE 2: Vt split: Chi/Clo[n][m] (transposed, +bias).
template<int MODE>
__global__ __launch_bounds__(256) void gemm_bt(
    const float* __restrict__ A,
    const ushort_t* __restrict__ Bh, const ushort_t* __restrict__ Bl,
    const float* __restrict__ bias, float scale,
    float* __restrict__ Cf, ushort_t* __restrict__ Chi, ushort_t* __restrict__ Clo)
{
  const int tid = threadIdx.x;
  const int w = tid >> 6, l = tid & 63;
  const int row16 = l & 15, grp = l >> 4;
  const int bm = blockIdx.y * 128, bn = blockIdx.x * 128;
  const int r0 = bm + w * 32;

  f32x4 acc[2][8];
  #pragma unroll
  for (int mi = 0; mi < 2; ++mi)
    #pragma unroll
    for (int ni = 0; ni < 8; ++ni)
      #pragma unroll
      for (int r = 0; r < 4; ++r) acc[mi][ni][r] = 0.f;

  const float* a0 = A + (size_t)(r0 + row16) * H_DIM + grp * 8;
  const ushort_t* bh0 = Bh + (size_t)(bn + row16) * H_DIM + grp * 8;
  const ushort_t* bl0 = Bl + (size_t)(bn + row16) * H_DIM + grp * 8;

  for (int kc = 0; kc < H_DIM; kc += 32) {
    short8 ah[2], al[2];
    #pragma unroll
    for (int mi = 0; mi < 2; ++mi) {
      float xs[8];
      float4 xa = *(const float4*)(a0 + (size_t)mi * 16 * H_DIM + kc);
      float4 xb = *(const float4*)(a0 + (size_t)mi * 16 * H_DIM + kc + 4);
      xs[0] = xa.x; xs[1] = xa.y; xs[2] = xa.z; xs[3] = xa.w;
      xs[4] = xb.x; xs[5] = xb.y; xs[6] = xb.z; xs[7] = xb.w;
      #pragma unroll
      for (int j = 0; j < 8; ++j) {
        unsigned short hh = f2bf(xs[j]);
        ah[mi][j] = (short)hh;
        al[mi][j] = (short)f2bf(xs[j] - bf2f(hh));
      }
    }
    #pragma unroll
    for (int ni = 0; ni < 8; ++ni) {
      short8 bh = *(const short8*)(bh0 + (size_t)ni * 16 * H_DIM + kc);
      short8 bl = *(const short8*)(bl0 + (size_t)ni * 16 * H_DIM + kc);
      #pragma unroll
      for (int mi = 0; mi < 2; ++mi) {
        acc[mi][ni] = __builtin_amdgcn_mfma_f32_16x16x32_bf16(ah[mi], bh, acc[mi][ni], 0, 0, 0);
        acc[mi][ni] = __builtin_amdgcn_mfma_f32_16x16x32_bf16(al[mi], bh, acc[mi][ni], 0, 0, 0);
        acc[mi][ni] = __builtin_amdgcn_mfma_f32_16x16x32_bf16(ah[mi], bl, acc[mi][ni], 0, 0, 0);
      }
    }
  }

  if (MODE == 0) {
    #pragma unroll
    for (int ni = 0; ni < 8; ++ni) {
      float bcol = bias[bn + ni * 16 + row16];
      #pragma unroll
      for (int mi = 0; mi < 2; ++mi)
        #pragma unroll
        for (int r = 0; r < 4; ++r)
          Cf[(size_t)(r0 + mi * 16 + grp * 4 + r) * H_DIM + bn + ni * 16 + row16] =
              acc[mi][ni][r] + bcol;
    }
  } else if (MODE == 1) {
    // rope: head-local dim d = ni*16+row16 (<64 for ni<4) pairs with d+64 (ni+4).
    float bA[8];
    #pragma unroll
    for (int ni = 0; ni < 8; ++ni) bA[ni] = bias[bn + ni * 16 + row16];
    float invf[4];
    #pragma unroll
    for (int ni = 0; ni < 4; ++ni) {
      int p = ni * 16 + row16;
      invf[ni] = (float)pow(10000.0, -(double)p * (1.0 / 64.0));
    }
    #pragma unroll
    for (int mi = 0; mi < 2; ++mi)
      #pragma unroll
      for (int r = 0; r < 4; ++r) {
        int row = r0 + mi * 16 + grp * 4 + r;
        #pragma unroll
        for (int ni = 0; ni < 4; ++ni) {
          float sv, cv;
          sincosf((float)row * invf[ni], &sv, &cv);
          float v0 = acc[mi][ni][r] + bA[ni];
          float v1 = acc[mi][ni + 4][r] + bA[ni + 4];
          float o0 = (v0 * cv - v1 * sv) * scale;
          float o1 = (v1 * cv + v0 * sv) * scale;
          size_t base = (size_t)row * H_DIM + bn + row16;
          unsigned short h0 = f2bf(o0);
          Chi[base + ni * 16] = h0;
          Clo[base + ni * 16] = f2bf(o0 - bf2f(h0));
          unsigned short h1 = f2bf(o1);
          Chi[base + ni * 16 + 64] = h1;
          Clo[base + ni * 16 + 64] = f2bf(o1 - bf2f(h1));
        }
      }
  } else {
    // Vt: Chi/Clo[n = col][m = seq row], 4 consecutive rows per store.
    #pragma unroll
    for (int ni = 0; ni < 8; ++ni) {
      float bcol = bias[bn + ni * 16 + row16];
      int col = bn + ni * 16 + row16;
      #pragma unroll
      for (int mi = 0; mi < 2; ++mi) {
        int rowb = r0 + mi * 16 + grp * 4;
        ushort_t h4[4], l4[4];
        #pragma unroll
        for (int r = 0; r < 4; ++r) {
          float x = acc[mi][ni][r] + bcol;
          h4[r] = f2bf(x);
          l4[r] = f2bf(x - bf2f(h4[r]));
        }
        size_t o = (size_t)col * S_DIM + rowb;
        *(uint2*)(Chi + o) = *(const uint2*)h4;
        *(uint2*)(Clo + o) = *(const uint2*)l4;
      }
    }
  }
}

// ---------- MFMA flash attention (Q/K pre-roped+split, V transposed+split) ----------
__global__ __launch_bounds__(256) void attn_mfma(
    const ushort_t* __restrict__ Qhi, const ushort_t* __restrict__ Qlo,
    const ushort_t* __restrict__ Khi, const ushort_t* __restrict__ Klo,
    const ushort_t* __restrict__ Vhi, const ushort_t* __restrict__ Vlo,
    float* __restrict__ O)
{
  __shared__ unsigned int Pds[4][16][36];   // per-wave P tile, hi|lo<<16 packed
  const int tid = threadIdx.x;
  const int w = tid >> 6;
  const int l = tid & 63;
  const int row16 = l & 15;
  const int grp = l >> 4;
  const int h = blockIdx.y;
  const int qbase = blockIdx.x * 64 + w * 16;
  const int qpos = qbase + row16;

  short8 qhi[4], qlo[4];
  {
    size_t qoff = (size_t)qpos * H_DIM + h * HD + grp * 8;
    #pragma unroll
    for (int s = 0; s < 4; ++s) {
      qhi[s] = *(const short8*)(Qhi + qoff + s * 32);
      qlo[s] = *(const short8*)(Qlo + qoff + s * 32);
    }
  }

  f32x4 oacc[8];
  #pragma unroll
  for (int d = 0; d < 8; ++d)
    #pragma unroll
    for (int r = 0; r < 4; ++r) oacc[d][r] = 0.f;
  float m[4], lsum[4];
  #pragma unroll
  for (int r = 0; r < 4; ++r) { m[r] = -INFINITY; lsum[r] = 0.f; }

  const ushort_t* kh_base = Khi + h * HD + grp * 8;
  const ushort_t* kl_base = Klo + h * HD + grp * 8;
  const ushort_t* vh_base = Vhi + (size_t)(h * HD + row16) * S_DIM + grp * 8;
  const ushort_t* vl_base = Vlo + (size_t)(h * HD + row16) * S_DIM + grp * 8;

  for (int kt = 0; kt < S_DIM / 32; ++kt) {
    const int k0 = kt * 32 + row16;
    f32x4 s0 = {0.f, 0.f, 0.f, 0.f};
    f32x4 s1 = {0.f, 0.f, 0.f, 0.f};
    #pragma unroll
    for (int s = 0; s < 4; ++s) {
      short8 b0h = *(const short8*)(kh_base + (size_t)k0 * H_DIM + s * 32);
      short8 b0l = *(const short8*)(kl_base + (size_t)k0 * H_DIM + s * 32);
      short8 b1h = *(const short8*)(kh_base + (size_t)(k0 + 16) * H_DIM + s * 32);
      short8 b1l = *(const short8*)(kl_base + (size_t)(k0 + 16) * H_DIM + s * 32);
      s0 = __builtin_amdgcn_mfma_f32_16x16x32_bf16(qhi[s], b0h, s0, 0, 0, 0);
      s0 = __builtin_amdgcn_mfma_f32_16x16x32_bf16(qlo[s], b0h, s0, 0, 0, 0);
      s0 = __builtin_amdgcn_mfma_f32_16x16x32_bf16(qhi[s], b0l, s0, 0, 0, 0);
      s1 = __builtin_amdgcn_mfma_f32_16x16x32_bf16(qhi[s], b1h, s1, 0, 0, 0);
      s1 = __builtin_amdgcn_mfma_f32_16x16x32_bf16(qlo[s], b1h, s1, 0, 0, 0);
      s1 = __builtin_amdgcn_mfma_f32_16x16x32_bf16(qhi[s], b1l, s1, 0, 0, 0);
    }

    float corr[4], p0v[4], p1v[4];
    #pragma unroll
    for (int r = 0; r < 4; ++r) {
      float x = fmaxf(s0[r], s1[r]);
      x = fmaxf(x, __shfl_xor(x, 1));
      x = fmaxf(x, __shfl_xor(x, 2));
      x = fmaxf(x, __shfl_xor(x, 4));
      x = fmaxf(x, __shfl_xor(x, 8));
      float mn = fmaxf(m[r], x);
      corr[r] = __expf(m[r] - mn);
      m[r] = mn;
    }
    #pragma unroll
    for (int r = 0; r < 4; ++r) {
      p0v[r] = __expf(s0[r] - m[r]);
      p1v[r] = __expf(s1[r] - m[r]);
      float t = p0v[r] + p1v[r];
      t += __shfl_xor(t, 1);
      t += __shfl_xor(t, 2);
      t += __shfl_xor(t, 4);
      t += __shfl_xor(t, 8);
      lsum[r] = lsum[r] * corr[r] + t;
    }
    #pragma unroll
    for (int d = 0; d < 8; ++d)
      #pragma unroll
      for (int r = 0; r < 4; ++r) oacc[d][r] *= corr[r];

    #pragma unroll
    for (int r = 0; r < 4; ++r) {
      unsigned short h0 = f2bf(p0v[r]);
      unsigned lo0 = f2bf(p0v[r] - bf2f(h0));
      Pds[w][grp * 4 + r][row16] = (unsigned)h0 | (lo0 << 16);
      unsigned short h1 = f2bf(p1v[r]);
      unsigned lo1 = f2bf(p1v[r] - bf2f(h1));
      Pds[w][grp * 4 + r][row16 + 16] = (unsigned)h1 | (lo1 << 16);
    }
    const unsigned int* pr = &Pds[w][row16][grp * 8];
    uint4 dA = *(const uint4*)pr;
    uint4 dB = *(const uint4*)(pr + 4);
    unsigned dw[8] = {dA.x, dA.y, dA.z, dA.w, dB.x, dB.y, dB.z, dB.w};
    short8 phi, plo;
    #pragma unroll
    for (int j = 0; j < 8; ++j) {
      phi[j] = (short)(dw[j] & 0xffffu);
      plo[j] = (short)(dw[j] >> 16);
    }

    #pragma unroll
    for (int d = 0; d < 8; ++d) {
      short8 vh = *(const short8*)(vh_base + (size_t)d * 16 * S_DIM + kt * 32);
      short8 vl = *(const short8*)(vl_base + (size_t)d * 16 * S_DIM + kt * 32);
      oacc[d] = __builtin_amdgcn_mfma_f32_16x16x32_bf16(phi, vh, oacc[d], 0, 0, 0);
      oacc[d] = __builtin_amdgcn_mfma_f32_16x16x32_bf16(plo, vh, oacc[d], 0, 0, 0);
      oacc[d] = __builtin_amdgcn_mfma_f32_16x16x32_bf16(phi, vl, oacc[d], 0, 0, 0);
    }
  }

  float inv[4];
  #pragma unroll
  for (int r = 0; r < 4; ++r) inv[r] = 1.f / lsum[r];
  #pragma unroll
  for (int d = 0; d < 8; ++d)
    #pragma unroll
    for (int r = 0; r < 4; ++r)
      O[(size_t)(qbase + grp * 4 + r) * H_DIM + h * HD + d * 16 + row16] =
          oacc[d][r] * inv[r];
}

// ---------------- launch ----------------
extern "C" void kernel_launch(void* const* d_in, const int* in_sizes, int n_in,
                              void* d_out, int out_size, void* d_ws, size_t ws_size,
                              hipStream_t stream)
{
  const float* X  = (const float*)d_in[0];
  const float* wq = (const float*)d_in[1];
  const float* bq = (const float*)d_in[2];
  const float* wk = (const float*)d_in[3];
  const float* bk = (const float*)d_in[4];
  const float* wv = (const float*)d_in[5];
  const float* bv = (const float*)d_in[6];
  const float* wo = (const float*)d_in[7];
  const float* bo = (const float*)d_in[8];
  float* out = (float*)d_out;

  // 8 bf16 slabs of S*H ushorts = 67.1 MB total (same footprint as the passing run).
  char* ws = (char*)d_ws;
  const size_t slabB = (size_t)S_DIM * H_DIM * sizeof(ushort_t);  // 8.39 MB
  ushort_t* Qhi = (ushort_t*)(ws + 0 * slabB);   // after attn: reused for Wo^T hi
  ushort_t* Qlo = (ushort_t*)(ws + 1 * slabB);   //                       Wo^T lo
  ushort_t* Wth = (ushort_t*)(ws + 2 * slabB);   // reused Wt slab (q,k,v); then O fp32
  ushort_t* Wtl = (ushort_t*)(ws + 3 * slabB);
  ushort_t* Khi = (ushort_t*)(ws + 4 * slabB);
  ushort_t* Klo = (ushort_t*)(ws + 5 * slabB);
  ushort_t* Vth = (ushort_t*)(ws + 6 * slabB);
  ushort_t* Vtl = (ushort_t*)(ws + 7 * slabB);
  float* Of32 = (float*)(ws + 2 * slabB);        // 16.8 MB over slabs 2-3 (Wt dead)
  ushort_t* Woth = Qhi;                          // slabs 0-1 (Q dead after attn)
  ushort_t* Wotl = Qlo;

  dim3 gT(32, 32);
  dim3 gG(H_DIM / 128, S_DIM / 128);  // (16,16)
  dim3 gA(S_DIM / 64, NH);            // (32,16)

  transpose_split<<<gT, 256, 0, stream>>>(wq, Wth, Wtl);
  gemm_bt<1><<<gG, 256, 0, stream>>>(X, Wth, Wtl, bq, QSCALE, nullptr, Qhi, Qlo);

  transpose_split<<<gT, 256, 0, stream>>>(wk, Wth, Wtl);
  gemm_bt<1><<<gG, 256, 0, stream>>>(X, Wth, Wtl, bk, 1.0f, nullptr, Khi, Klo);

  transpose_split<<<gT, 256, 0, stream>>>(wv, Wth, Wtl);
  gemm_bt<2><<<gG, 256, 0, stream>>>(X, Wth, Wtl, bv, 1.0f, nullptr, Vth, Vtl);

  attn_mfma<<<gA, 256, 0, stream>>>(Qhi, Qlo, Khi, Klo, Vth, Vtl, Of32);

  transpose_split<<<gT, 256, 0, stream>>>(wo, Woth, Wotl);
  gemm_bt<0><<<gG, 256, 0, stream>>>(Of32, Woth, Wotl, bo, 1.0f, out, nullptr, nullptr);
}